// Round 7
// baseline (317.178 us; speedup 1.0000x reference)
//
#include <hip/hip_runtime.h>

constexpr int Hh = 320, Ww = 320, Cc = 32, Bb = 4, Nn = 20000;
constexpr int HWp = Hh * Ww;
constexpr int NB = 768;  // 3 blocks/CU x 256 CUs, guaranteed resident via launch_bounds
constexpr int PROJ_BLOCKS_PER_SB = 157;              // ceil(20000/128)
constexpr int PROJ_TOTAL = PROJ_BLOCKS_PER_SB * 8;   // 1256
constexpr int BUILD_BLOCKS = 625;                    // 160000/256 exact
constexpr int P1_TOTAL = PROJ_TOTAL + BUILD_BLOCKS + 3;
constexpr int ATTN_PER_SB = 79;                      // ceil(20000/256)
constexpr int P2_TOTAL = ATTN_PER_SB * 8;            // 632 (< NB: one vb per block)

// Device-scope grid barrier; all NB blocks are resident (persistent kernel).
__device__ __forceinline__ void gbar(int* cnt, int* flg) {
  __syncthreads();
  if (threadIdx.x == 0) {
    __threadfence();  // release: L2 writeback so other XCDs see phase writes
    if (atomicAdd(cnt, 1) == NB - 1) {
      atomicExch(flg, 1);
    } else {
      while (atomicAdd(flg, 0) == 0) __builtin_amdgcn_s_sleep(8);
    }
    __threadfence();  // acquire: invalidate caches before reading phase data
  }
  __syncthreads();
}

__global__ __launch_bounds__(256, 3) void mega_k(
    const float* __restrict__ li_feats, const float* __restrict__ ra_feats,
    const int* __restrict__ li_coors, const int* __restrict__ ra_coors,
    const float* __restrict__ pos,
    const float* __restrict__ in_w1, const float* __restrict__ in_b1,
    const float* __restrict__ out_w1, const float* __restrict__ out_b1,
    const float* __restrict__ in_w2, const float* __restrict__ in_b2,
    const float* __restrict__ out_w2, const float* __restrict__ out_b2,
    int* __restrict__ grids, float* __restrict__ Qh, float* __restrict__ Kp,
    float* __restrict__ Vp, float* __restrict__ out_pts,
    float* __restrict__ posv, int* __restrict__ bars,
    float* __restrict__ out) {
  __shared__ __align__(16) float wqT[32 * 36], wkT[32 * 36], wvT[32 * 36];
  __shared__ float bq[Cc];
  __shared__ __align__(16) float ow[Cc * Cc], pvs[9 * Cc];
  __shared__ float obias[Cc], bk[Cc], bv[Cc];
  int t = threadIdx.x;
  int bid = blockIdx.x;

  // ================= Phase 1: posv + build_grid + QKV projection ============
  for (int vb = bid; vb < P1_TOTAL; vb += NB) {
    if (vb < PROJ_TOTAL) {
      int sb = vb / PROJ_BLOCKS_PER_SB;
      int blk = vb - sb * PROJ_BLOCKS_PER_SB;
      int src = sb >> 2, b = sb & 3;
      const float* wA = src == 0 ? in_w1 : in_w2;  // q weights: own direction
      const float* bA = src == 0 ? in_b1 : in_b2;
      const float* wB = src == 0 ? in_w2 : in_w1;  // k/v weights: other dir
      __syncthreads();  // protect LDS reuse across vb iterations
      for (int i = t; i < Cc * Cc; i += 256) {
        int c = i >> 5, j = i & 31;
        wqT[j * 36 + c] = wA[i];
        wkT[j * 36 + c] = wB[Cc * Cc + i];
        wvT[j * 36 + c] = wB[2 * Cc * Cc + i];
      }
      if (t < Cc) bq[t] = bA[t];
      __syncthreads();
      int quad = t >> 3, c4 = t & 7;
      int n0 = blk * 128 + quad * 4;
      if (n0 + 4 > Nn) n0 = Nn - 4;  // tail clamp: redundant idempotent work
      const float* f =
          (src == 0 ? li_feats : ra_feats) + ((size_t)b * Nn + n0) * Cc;
      const float4* wq4 = (const float4*)wqT;
      const float4* wk4 = (const float4*)wkT;
      const float4* wv4 = (const float4*)wvT;
      float4 bq4 = *(const float4*)(bq + c4 * 4);
      float4 aq[4], ak[4], av[4];
#pragma unroll
      for (int i = 0; i < 4; i++) {
        aq[i] = bq4;
        ak[i] = make_float4(0.f, 0.f, 0.f, 0.f);
        av[i] = make_float4(0.f, 0.f, 0.f, 0.f);
      }
#pragma unroll
      for (int j4 = 0; j4 < 8; j4++) {
        float fjs[4][4];
#pragma unroll
        for (int i = 0; i < 4; i++) {
          float4 v = ((const float4*)(f + i * Cc))[j4];
          fjs[i][0] = v.x; fjs[i][1] = v.y; fjs[i][2] = v.z; fjs[i][3] = v.w;
        }
#pragma unroll
        for (int u = 0; u < 4; u++) {
          int j = j4 * 4 + u;
          float4 q4 = wq4[j * 9 + c4];
          float4 k4 = wk4[j * 9 + c4];
          float4 v4 = wv4[j * 9 + c4];
#pragma unroll
          for (int i = 0; i < 4; i++) {
            float fj = fjs[i][u];
            aq[i].x += fj * q4.x; aq[i].y += fj * q4.y;
            aq[i].z += fj * q4.z; aq[i].w += fj * q4.w;
            ak[i].x += fj * k4.x; ak[i].y += fj * k4.y;
            ak[i].z += fj * k4.z; ak[i].w += fj * k4.w;
            av[i].x += fj * v4.x; av[i].y += fj * v4.y;
            av[i].z += fj * v4.z; av[i].w += fj * v4.w;
          }
        }
      }
      int dirq = src, dirkv = 1 - src;
      size_t qbase = (((size_t)dirq * Bb + b) * Nn + n0) * Cc + c4 * 4;
      size_t kvbase = (((size_t)dirkv * Bb + b) * Nn + n0) * Cc + c4 * 4;
#pragma unroll
      for (int i = 0; i < 4; i++) {
        *(float4*)(Qh + qbase + i * Cc) = aq[i];
        *(float4*)(Kp + kvbase + i * Cc) = ak[i];
        *(float4*)(Vp + kvbase + i * Cc) = av[i];
      }
    } else if (vb < PROJ_TOTAL + BUILD_BLOCKS) {
      int idx = (vb - PROJ_TOTAL) * 256 + t;  // [0, 160000) exact
      int src = idx / (Bb * Nn);
      int r = idx - src * (Bb * Nn);
      int b = r / Nn, n = r - b * Nn;
      const int* c = (src == 0 ? li_coors : ra_coors) + ((size_t)b * Nn + n) * 2;
      grids[((size_t)src * Bb + b) * HWp + c[0] * Ww + c[1]] = n;
      // no fill needed: readers verify coords (stale cells can never verify)
    } else {
      int tt = (vb - PROJ_TOTAL - BUILD_BLOCKS) * 256 + t;
      if (tt < 2 * 9 * Cc) {
        int dir = tt / (9 * Cc);
        int rem = tt - dir * 9 * Cc;
        int l = rem / Cc, ch = rem - l * Cc;
        const float* w = (dir == 0 ? in_w1 : in_w2) + (2 * Cc + ch) * Cc;
        const float* pl = pos + l * Cc;
        float acc = 0.f;
        for (int j = 0; j < Cc; j++) acc += pl[j] * w[j];
        posv[tt] = acc;
      }
    }
  }
  gbar(&bars[0], &bars[1]);

  // ================= Phase 2: per-point attention + out-projection ==========
  if (bid < P2_TOTAL) {
    int db = bid / ATTN_PER_SB;
    int bx = bid - db * ATTN_PER_SB;
    int dir = db >> 2, b = db & 3;
    const float* owp = dir == 0 ? out_w1 : out_w2;
    const float* obp = dir == 0 ? out_b1 : out_b2;
    const float* ibp = dir == 0 ? in_b1 : in_b2;
    for (int i = t; i < Cc * Cc; i += 256) ow[i] = owp[i];
    for (int i = t; i < 9 * Cc; i += 256) pvs[i] = posv[dir * 9 * Cc + i];
    if (t < Cc) {
      obias[t] = obp[t]; bk[t] = ibp[Cc + t]; bv[t] = ibp[2 * Cc + t];
    }
    __syncthreads();
    int n = bx * 256 + t;
    if (n < Nn) {
      const int* qc = (dir == 0 ? li_coors : ra_coors) + ((size_t)b * Nn + n) * 2;
      int y = qc[0], x = qc[1];
      // kv side: dir0 attends over ra (src1), dir1 over li (src0)
      const int* g = grids + ((size_t)(1 - dir) * Bb + b) * HWp;
      const int2* kvc =
          (const int2*)((dir == 0 ? ra_coors : li_coors) + (size_t)b * Nn * 2);
      float4 qh4[8];
      const float4* qp =
          (const float4*)(Qh + (((size_t)dir * Bb + b) * Nn + n) * Cc);
#pragma unroll
      for (int j = 0; j < 8; j++) qh4[j] = qp[j];
      float sinv0 = 0.f, sinv1 = 0.f;
      const float4* bk4 = (const float4*)bk;
#pragma unroll
      for (int j4 = 0; j4 < 4; j4++) {
        float4 b4 = bk4[j4], q4 = qh4[j4];
        sinv0 += q4.x * b4.x + q4.y * b4.y + q4.z * b4.z + q4.w * b4.w;
      }
#pragma unroll
      for (int j4 = 4; j4 < 8; j4++) {
        float4 b4 = bk4[j4], q4 = qh4[j4];
        sinv1 += q4.x * b4.x + q4.y * b4.y + q4.z * b4.z + q4.w * b4.w;
      }
      sinv0 *= 0.25f;
      sinv1 *= 0.25f;
      const int DY[9] = {0, -1, 1, 0, -1, 1, 0, -1, 1};
      const int DX[9] = {0, 0, 0, 1, 1, 1, -1, -1, -1};
      int sel[9];
      float s0[9], s1[9];
      const float* Kpb = Kp + ((size_t)dir * Bb + b) * Nn * Cc;
#pragma unroll
      for (int l = 0; l < 9; l++) {
        int cy = y + DY[l], cx = x + DX[l];
        int se = -1;
        if ((unsigned)cy < (unsigned)Hh && (unsigned)cx < (unsigned)Ww) {
          int cand = g[cy * Ww + cx];
          if (cand >= 0 && cand < Nn) {
            int2 cc2 = kvc[cand];
            if (cc2.x == cy && cc2.y == cx) se = cand;  // verify (no fill)
          }
        }
        sel[l] = se;
        float d0 = 0.f, d1 = 0.f;
        if (se >= 0) {
          const float4* kp = (const float4*)(Kpb + (size_t)se * Cc);
#pragma unroll
          for (int j4 = 0; j4 < 4; j4++) {
            float4 k4 = kp[j4], q4 = qh4[j4];
            d0 += q4.x * k4.x + q4.y * k4.y + q4.z * k4.z + q4.w * k4.w;
          }
#pragma unroll
          for (int j4 = 4; j4 < 8; j4++) {
            float4 k4 = kp[j4], q4 = qh4[j4];
            d1 += q4.x * k4.x + q4.y * k4.y + q4.z * k4.z + q4.w * k4.w;
          }
        }
        s0[l] = sinv0 + 0.25f * d0;
        s1[l] = sinv1 + 0.25f * d1;
      }
      float m0 = s0[0], m1 = s1[0];
#pragma unroll
      for (int l = 1; l < 9; l++) { m0 = fmaxf(m0, s0[l]); m1 = fmaxf(m1, s1[l]); }
      float sum0 = 0.f, sum1 = 0.f;
#pragma unroll
      for (int l = 0; l < 9; l++) {
        s0[l] = __expf(s0[l] - m0);
        s1[l] = __expf(s1[l] - m1);
        sum0 += s0[l];
        sum1 += s1[l];
      }
      float o[Cc];
#pragma unroll
      for (int j = 0; j < Cc; j++) o[j] = 0.f;
      const float* Vpb = Vp + ((size_t)dir * Bb + b) * Nn * Cc;
      const float4* pv4 = (const float4*)pvs;
#pragma unroll
      for (int l = 0; l < 9; l++) {
        int se = sel[l];
        if (se >= 0) {
          const float4* vp = (const float4*)(Vpb + (size_t)se * Cc);
          float w0 = s0[l], w1 = s1[l];
#pragma unroll
          for (int j4 = 0; j4 < 8; j4++) {
            float4 v4 = vp[j4];
            float4 p4 = pv4[l * 8 + j4];
            float w = (j4 < 4) ? w0 : w1;
            o[j4 * 4 + 0] += w * (v4.x + p4.x);
            o[j4 * 4 + 1] += w * (v4.y + p4.y);
            o[j4 * 4 + 2] += w * (v4.z + p4.z);
            o[j4 * 4 + 3] += w * (v4.w + p4.w);
          }
        }
      }
      float r0 = 1.f / sum0, r1 = 1.f / sum1;
#pragma unroll
      for (int j = 0; j < 16; j++) o[j] = o[j] * r0 + bv[j];
#pragma unroll
      for (int j = 16; j < Cc; j++) o[j] = o[j] * r1 + bv[j];
      float* op = out_pts + (((size_t)dir * Bb + b) * Nn + n) * Cc;
      const float4* ow4 = (const float4*)ow;
#pragma unroll
      for (int c0 = 0; c0 < Cc; c0 += 4) {
        float a[4];
#pragma unroll
        for (int u = 0; u < 4; u++) {
          float acc = obias[c0 + u];
#pragma unroll
          for (int j4 = 0; j4 < 8; j4++) {
            float4 w4 = ow4[(c0 + u) * 8 + j4];
            acc += o[j4 * 4 + 0] * w4.x + o[j4 * 4 + 1] * w4.y +
                   o[j4 * 4 + 2] * w4.z + o[j4 * 4 + 3] * w4.w;
          }
          a[u] = acc;
        }
        *(float4*)(op + c0) = make_float4(a[0], a[1], a[2], a[3]);
      }
    }
  }
  gbar(&bars[2], &bars[3]);

  // ================= Phase 3: inverted scatter to canvas ====================
  int gtid = bid * 256 + t;
  for (int i = gtid; i < 2 * Bb * HWp; i += NB * 256) {
    int db = i / HWp;
    int p = i - db * HWp;
    int dir = db >> 2, b = db & 3;
    const int* gq = grids + ((size_t)dir * Bb + b) * HWp;
    const int2* qc2 =
        (const int2*)((dir == 0 ? li_coors : ra_coors) + (size_t)b * Nn * 2);
    int se = gq[p];
    bool ok = (se >= 0 && se < Nn);
    if (ok) {
      int2 c2 = qc2[se];
      ok = (c2.x * Ww + c2.y) == p;  // verify (no fill)
    }
    float* ob = out + (((size_t)dir * Bb + b) * Cc) * HWp + p;
    if (!ok) {
#pragma unroll
      for (int c = 0; c < Cc; c++) ob[(size_t)c * HWp] = 0.f;
    } else {
      const float4* sp =
          (const float4*)(out_pts + (((size_t)dir * Bb + b) * Nn + se) * Cc);
#pragma unroll
      for (int c4 = 0; c4 < 8; c4++) {
        float4 v = sp[c4];
        ob[(size_t)(c4 * 4 + 0) * HWp] = v.x;
        ob[(size_t)(c4 * 4 + 1) * HWp] = v.y;
        ob[(size_t)(c4 * 4 + 2) * HWp] = v.z;
        ob[(size_t)(c4 * 4 + 3) * HWp] = v.w;
      }
    }
  }
}

extern "C" void kernel_launch(void* const* d_in, const int* in_sizes, int n_in,
                              void* d_out, int out_size, void* d_ws, size_t ws_size,
                              hipStream_t stream) {
  const float* li_feats = (const float*)d_in[0];
  const int* li_coors = (const int*)d_in[1];
  const float* ra_feats = (const float*)d_in[2];
  const int* ra_coors = (const int*)d_in[3];
  const float* pos = (const float*)d_in[4];
  const float* in_w1 = (const float*)d_in[5];
  const float* in_b1 = (const float*)d_in[6];
  const float* out_w1 = (const float*)d_in[7];
  const float* out_b1 = (const float*)d_in[8];
  const float* in_w2 = (const float*)d_in[9];
  const float* in_b2 = (const float*)d_in[10];
  const float* out_w2 = (const float*)d_in[11];
  const float* out_b2 = (const float*)d_in[12];

  char* ws = (char*)d_ws;
  size_t off = 0;
  int* grids = (int*)(ws + off);
  off += (size_t)2 * Bb * HWp * 4;  // 3,276,800 B
  float* Qh = (float*)(ws + off);
  off += (size_t)2 * Bb * Nn * Cc * 4;  // 20,480,000 B
  float* Kp = (float*)(ws + off);
  off += (size_t)2 * Bb * Nn * Cc * 4;
  float* Vp = (float*)(ws + off);
  off += (size_t)2 * Bb * Nn * Cc * 4;
  float* out_pts = (float*)(ws + off);
  off += (size_t)2 * Bb * Nn * Cc * 4;
  float* posv = (float*)(ws + off);
  off += (size_t)2 * 9 * Cc * 4;
  int* bars = (int*)(ws + off);
  off += 16;  // total ~85.2 MB

  hipMemsetAsync(bars, 0, 16, stream);
  mega_k<<<NB, 256, 0, stream>>>(li_feats, ra_feats, li_coors, ra_coors, pos,
                                 in_w1, in_b1, out_w1, out_b1, in_w2, in_b2,
                                 out_w2, out_b2, grids, Qh, Kp, Vp, out_pts,
                                 posv, bars, (float*)d_out);
}

// Round 9
// 127.138 us; speedup vs baseline: 2.4948x; 2.4948x over previous
//
#include <hip/hip_runtime.h>

constexpr int Hh = 320, Ww = 320, Cc = 32, Bb = 4, Nn = 20000;
constexpr int HWp = Hh * Ww;

__device__ __forceinline__ float4 shfl_xor4(float4 v, int m) {
  return make_float4(__shfl_xor(v.x, m), __shfl_xor(v.y, m),
                     __shfl_xor(v.z, m), __shfl_xor(v.w, m));
}

// Fused: blocks [0, PROJ_TOTAL) = Q/K/V projection (register-tiled, 4 pts/thread);
// blocks [PROJ_TOTAL, +BUILD_BLOCKS) = build_grid scatter (no fill: verify-on-read);
// last 3 blocks = posv[dir][l][c] = pos[l] @ wv_dir.T
constexpr int PROJ_BLOCKS_PER_SB = 157;              // ceil(20000/128)
constexpr int PROJ_TOTAL = PROJ_BLOCKS_PER_SB * 8;   // 1256
constexpr int BUILD_BLOCKS = 625;                    // 160000/256 exact

__global__ __launch_bounds__(256) void project_build_k(
    const float* __restrict__ li_feats, const float* __restrict__ ra_feats,
    const int* __restrict__ li_coors, const int* __restrict__ ra_coors,
    const float* __restrict__ pos,
    const float* __restrict__ in_w1, const float* __restrict__ in_b1,
    const float* __restrict__ in_w2, const float* __restrict__ in_b2,
    float* __restrict__ Qh, float* __restrict__ Kp, float* __restrict__ Vp,
    int* __restrict__ grids, float* __restrict__ posv) {
  int bx = blockIdx.x;
  if (bx >= PROJ_TOTAL) {
    if (bx < PROJ_TOTAL + BUILD_BLOCKS) {
      int idx = (bx - PROJ_TOTAL) * 256 + threadIdx.x;  // [0, 160000) exact
      int src = idx / (Bb * Nn);
      int r = idx - src * (Bb * Nn);
      int b = r / Nn, n = r - b * Nn;
      const int* c = (src == 0 ? li_coors : ra_coors) + ((size_t)b * Nn + n) * 2;
      grids[((size_t)src * Bb + b) * HWp + c[0] * Ww + c[1]] = n;
    } else {
      int tt = (bx - PROJ_TOTAL - BUILD_BLOCKS) * 256 + threadIdx.x;
      if (tt < 2 * 9 * Cc) {
        int dir = tt / (9 * Cc);
        int rem = tt - dir * 9 * Cc;
        int l = rem / Cc, ch = rem - l * Cc;
        const float* w = (dir == 0 ? in_w1 : in_w2) + (2 * Cc + ch) * Cc;
        const float* pl = pos + l * Cc;
        float acc = 0.f;
        for (int j = 0; j < Cc; j++) acc += pl[j] * w[j];
        posv[tt] = acc;
      }
    }
    return;
  }
  int sb = bx / PROJ_BLOCKS_PER_SB;
  int blk = bx - sb * PROJ_BLOCKS_PER_SB;
  int src = sb >> 2, b = sb & 3;
  // weights transposed, rows padded to 36 floats (9 float4) for bank spread
  __shared__ __align__(16) float wqT[32 * 36];
  __shared__ __align__(16) float wkT[32 * 36];
  __shared__ __align__(16) float wvT[32 * 36];
  __shared__ float bq[Cc];
  const float* wA = src == 0 ? in_w1 : in_w2;  // q weights: own direction
  const float* bA = src == 0 ? in_b1 : in_b2;
  const float* wB = src == 0 ? in_w2 : in_w1;  // k/v weights: other direction
  int t = threadIdx.x;
  for (int i = t; i < Cc * Cc; i += 256) {
    int c = i >> 5, j = i & 31;
    wqT[j * 36 + c] = wA[i];
    wkT[j * 36 + c] = wB[Cc * Cc + i];
    wvT[j * 36 + c] = wB[2 * Cc * Cc + i];
  }
  if (t < Cc) bq[t] = bA[t];
  __syncthreads();
  int quad = t >> 3, c4 = t & 7;
  int n0 = blk * 128 + quad * 4;
  if (n0 + 4 > Nn) n0 = Nn - 4;  // tail clamp: redundant idempotent work
  const float* f = (src == 0 ? li_feats : ra_feats) + ((size_t)b * Nn + n0) * Cc;
  const float4* wq4 = (const float4*)wqT;
  const float4* wk4 = (const float4*)wkT;
  const float4* wv4 = (const float4*)wvT;
  float4 bq4 = *(const float4*)(bq + c4 * 4);
  float4 aq[4], ak[4], av[4];
#pragma unroll
  for (int i = 0; i < 4; i++) {
    aq[i] = bq4;
    ak[i] = make_float4(0.f, 0.f, 0.f, 0.f);
    av[i] = make_float4(0.f, 0.f, 0.f, 0.f);
  }
#pragma unroll
  for (int j4 = 0; j4 < 8; j4++) {
    float fjs[4][4];
#pragma unroll
    for (int i = 0; i < 4; i++) {
      float4 v = ((const float4*)(f + i * Cc))[j4];
      fjs[i][0] = v.x; fjs[i][1] = v.y; fjs[i][2] = v.z; fjs[i][3] = v.w;
    }
#pragma unroll
    for (int u = 0; u < 4; u++) {
      int j = j4 * 4 + u;
      float4 q4 = wq4[j * 9 + c4];
      float4 k4 = wk4[j * 9 + c4];
      float4 v4 = wv4[j * 9 + c4];
#pragma unroll
      for (int i = 0; i < 4; i++) {
        float fj = fjs[i][u];
        aq[i].x += fj * q4.x; aq[i].y += fj * q4.y;
        aq[i].z += fj * q4.z; aq[i].w += fj * q4.w;
        ak[i].x += fj * k4.x; ak[i].y += fj * k4.y;
        ak[i].z += fj * k4.z; ak[i].w += fj * k4.w;
        av[i].x += fj * v4.x; av[i].y += fj * v4.y;
        av[i].z += fj * v4.z; av[i].w += fj * v4.w;
      }
    }
  }
  int dirkv = 1 - src;
  size_t qbase = (((size_t)src * Bb + b) * Nn + n0) * Cc + c4 * 4;
  size_t kvbase = (((size_t)dirkv * Bb + b) * Nn + n0) * Cc + c4 * 4;
#pragma unroll
  for (int i = 0; i < 4; i++) {
    *(float4*)(Qh + qbase + i * Cc) = aq[i];
    *(float4*)(Kp + kvbase + i * Cc) = ak[i];
    *(float4*)(Vp + kvbase + i * Cc) = av[i];
  }
}

// 8-lane-per-point attention + in-kernel output projection.
// Block = 32 points x 8 lanes; lane owns channels [4*c4, 4*c4+4).
// K/V gathers: one float4/lane (8 lanes = the full 128B line); head dots
// reduced via shfl_xor(1,2) within each 4-lane head group. After PV+bias the
// lane holds its 4-channel slice of o; out-projection assembles all 32 via 8
// xor-rotations of the point's lanes, reading ow from LDS (conflict-free).
__global__ __launch_bounds__(256) void attn8_k(
    const int* __restrict__ li_coors, const int* __restrict__ ra_coors,
    const int* __restrict__ grids, const float* __restrict__ Qh,
    const float* __restrict__ Kp, const float* __restrict__ Vp,
    const float* __restrict__ posv, const float* __restrict__ in_b1,
    const float* __restrict__ in_b2, const float* __restrict__ out_w1,
    const float* __restrict__ out_b1, const float* __restrict__ out_w2,
    const float* __restrict__ out_b2, float* __restrict__ out_pts) {
  int db = blockIdx.y;
  int dir = db >> 2, b = db & 3;
  __shared__ __align__(16) float ow[Cc * Cc];
  __shared__ __align__(16) float pv[9 * Cc];
  __shared__ float sbk[Cc], sbv[Cc], sob[Cc];
  const float* owp = dir == 0 ? out_w1 : out_w2;
  const float* obp = dir == 0 ? out_b1 : out_b2;
  const float* ibp = dir == 0 ? in_b1 : in_b2;
  int t = threadIdx.x;
  for (int i = t; i < Cc * Cc; i += 256) ow[i] = owp[i];
  for (int i = t; i < 9 * Cc; i += 256) pv[i] = posv[dir * 9 * Cc + i];
  if (t < Cc) {
    sbk[t] = ibp[Cc + t];
    sbv[t] = ibp[2 * Cc + t];
    sob[t] = obp[t];
  }
  __syncthreads();
  int pt = t >> 3, c4 = t & 7;
  int n = blockIdx.x * 32 + pt;  // 625*32 == 20000 exact, no tail
  const int2* qcp =
      (const int2*)((dir == 0 ? li_coors : ra_coors) + (size_t)b * Nn * 2);
  int2 yx = qcp[n];
  int y = yx.x, x = yx.y;
  const int* g = grids + ((size_t)(1 - dir) * Bb + b) * HWp;
  const int2* kvc =
      (const int2*)((dir == 0 ? ra_coors : li_coors) + (size_t)b * Nn * 2);
  float4 qh4 =
      *(const float4*)(Qh + (((size_t)dir * Bb + b) * Nn + n) * Cc + c4 * 4);
  // invalid-slot score: qh . bk over the lane's head (reduce within 4 lanes)
  float4 bk4 = *(const float4*)(sbk + c4 * 4);
  float pb = qh4.x * bk4.x + qh4.y * bk4.y + qh4.z * bk4.z + qh4.w * bk4.w;
  pb += __shfl_xor(pb, 1);
  pb += __shfl_xor(pb, 2);
  const int DY[9] = {0, -1, 1, 0, -1, 1, 0, -1, 1};
  const int DX[9] = {0, 0, 0, 1, 1, 1, -1, -1, -1};
  int sel[9];
  float s[9];
  const float* Kpb = Kp + ((size_t)dir * Bb + b) * Nn * Cc;
#pragma unroll
  for (int l = 0; l < 9; l++) {
    int cy = y + DY[l], cx = x + DX[l];
    int se = -1;
    if ((unsigned)cy < (unsigned)Hh && (unsigned)cx < (unsigned)Ww) {
      int cand = g[cy * Ww + cx];
      if (cand >= 0 && cand < Nn) {
        int2 cc2 = kvc[cand];
        if (cc2.x == cy && cc2.y == cx) se = cand;  // verify (no grid fill)
      }
    }
    sel[l] = se;
    float d = 0.f;
    if (se >= 0) {
      float4 k4 = *(const float4*)(Kpb + (size_t)se * Cc + c4 * 4);
      d = qh4.x * k4.x + qh4.y * k4.y + qh4.z * k4.z + qh4.w * k4.w;
    }
    d += __shfl_xor(d, 1);
    d += __shfl_xor(d, 2);  // lane's head dot (0 if invalid)
    s[l] = 0.25f * (pb + d);
  }
  // softmax over 9 slots for the lane's head
  float m = s[0];
#pragma unroll
  for (int l = 1; l < 9; l++) m = fmaxf(m, s[l]);
  float sum = 0.f;
#pragma unroll
  for (int l = 0; l < 9; l++) {
    s[l] = __expf(s[l] - m);
    sum += s[l];
  }
  // PV on the lane's 4-channel slice
  float4 o4 = make_float4(0.f, 0.f, 0.f, 0.f);
  const float* Vpb = Vp + ((size_t)dir * Bb + b) * Nn * Cc;
#pragma unroll
  for (int l = 0; l < 9; l++) {
    int se = sel[l];
    if (se >= 0) {
      float4 v4 = *(const float4*)(Vpb + (size_t)se * Cc + c4 * 4);
      float4 p4 = *(const float4*)(pv + l * Cc + c4 * 4);
      float w = s[l];
      o4.x += w * (v4.x + p4.x);
      o4.y += w * (v4.y + p4.y);
      o4.z += w * (v4.z + p4.z);
      o4.w += w * (v4.w + p4.w);
    }
  }
  float r = 1.f / sum;
  float4 bv4 = *(const float4*)(sbv + c4 * 4);
  o4 = make_float4(o4.x * r + bv4.x, o4.y * r + bv4.y, o4.z * r + bv4.z,
                   o4.w * r + bv4.w);
  // output projection: lane computes out channels [4*c4, 4*c4+4)
  const float4* ow4 = (const float4*)ow;
  float4 sob4 = *(const float4*)(sob + c4 * 4);
  float acc0 = sob4.x, acc1 = sob4.y, acc2 = sob4.z, acc3 = sob4.w;
#pragma unroll
  for (int mm = 0; mm < 8; mm++) {
    float4 oj = shfl_xor4(o4, mm);  // o slice of group jb = c4 ^ mm
    int jb = c4 ^ mm;
    float4 w0 = ow4[(c4 * 4 + 0) * 8 + jb];
    float4 w1 = ow4[(c4 * 4 + 1) * 8 + jb];
    float4 w2 = ow4[(c4 * 4 + 2) * 8 + jb];
    float4 w3 = ow4[(c4 * 4 + 3) * 8 + jb];
    acc0 += oj.x * w0.x + oj.y * w0.y + oj.z * w0.z + oj.w * w0.w;
    acc1 += oj.x * w1.x + oj.y * w1.y + oj.z * w1.z + oj.w * w1.w;
    acc2 += oj.x * w2.x + oj.y * w2.y + oj.z * w2.z + oj.w * w2.w;
    acc3 += oj.x * w3.x + oj.y * w3.y + oj.z * w3.z + oj.w * w3.w;
  }
  *(float4*)(out_pts + (((size_t)dir * Bb + b) * Nn + n) * Cc + c4 * 4) =
      make_float4(acc0, acc1, acc2, acc3);
}

// Inverted scatter with verify-on-read: one thread per canvas pixel;
// channel stores are wave-coalesced full lines.
__global__ __launch_bounds__(256) void scatter_k(
    const int* __restrict__ grids, const int* __restrict__ li_coors,
    const int* __restrict__ ra_coors, const float* __restrict__ out_pts,
    float* __restrict__ out) {
  int db = blockIdx.y;
  int dir = db >> 2, b = db & 3;
  int p = blockIdx.x * 256 + threadIdx.x;
  const int* gq = grids + ((size_t)dir * Bb + b) * HWp;
  const int2* qc2 =
      (const int2*)((dir == 0 ? li_coors : ra_coors) + (size_t)b * Nn * 2);
  int se = gq[p];
  bool ok = (se >= 0 && se < Nn);
  if (ok) {
    int2 c2 = qc2[se];
    ok = (c2.x * Ww + c2.y) == p;  // verify (no grid fill)
  }
  float* ob = out + (((size_t)dir * Bb + b) * Cc) * HWp + p;
  if (!ok) {
#pragma unroll
    for (int c = 0; c < Cc; c++) ob[(size_t)c * HWp] = 0.f;
  } else {
    const float4* sp =
        (const float4*)(out_pts + (((size_t)dir * Bb + b) * Nn + se) * Cc);
#pragma unroll
    for (int c4 = 0; c4 < 8; c4++) {
      float4 v = sp[c4];
      ob[(size_t)(c4 * 4 + 0) * HWp] = v.x;
      ob[(size_t)(c4 * 4 + 1) * HWp] = v.y;
      ob[(size_t)(c4 * 4 + 2) * HWp] = v.z;
      ob[(size_t)(c4 * 4 + 3) * HWp] = v.w;
    }
  }
}

extern "C" void kernel_launch(void* const* d_in, const int* in_sizes, int n_in,
                              void* d_out, int out_size, void* d_ws, size_t ws_size,
                              hipStream_t stream) {
  const float* li_feats = (const float*)d_in[0];
  const int* li_coors = (const int*)d_in[1];
  const float* ra_feats = (const float*)d_in[2];
  const int* ra_coors = (const int*)d_in[3];
  const float* pos = (const float*)d_in[4];
  const float* in_w1 = (const float*)d_in[5];
  const float* in_b1 = (const float*)d_in[6];
  const float* out_w1 = (const float*)d_in[7];
  const float* out_b1 = (const float*)d_in[8];
  const float* in_w2 = (const float*)d_in[9];
  const float* in_b2 = (const float*)d_in[10];
  const float* out_w2 = (const float*)d_in[11];
  const float* out_b2 = (const float*)d_in[12];

  char* ws = (char*)d_ws;
  size_t off = 0;
  int* grids = (int*)(ws + off);
  off += (size_t)2 * Bb * HWp * 4;  // 3,276,800 B
  float* Qh = (float*)(ws + off);
  off += (size_t)2 * Bb * Nn * Cc * 4;  // 20,480,000 B
  float* Kp = (float*)(ws + off);
  off += (size_t)2 * Bb * Nn * Cc * 4;
  float* Vp = (float*)(ws + off);
  off += (size_t)2 * Bb * Nn * Cc * 4;
  float* out_pts = (float*)(ws + off);
  off += (size_t)2 * Bb * Nn * Cc * 4;
  float* posv = (float*)(ws + off);
  off += 2 * 9 * Cc * 4;  // total ~85.2 MB

  project_build_k<<<PROJ_TOTAL + BUILD_BLOCKS + 3, 256, 0, stream>>>(
      li_feats, ra_feats, li_coors, ra_coors, pos, in_w1, in_b1, in_w2, in_b2,
      Qh, Kp, Vp, grids, posv);
  dim3 ga(Nn / 32, 2 * Bb);
  attn8_k<<<ga, 256, 0, stream>>>(li_coors, ra_coors, grids, Qh, Kp, Vp, posv,
                                  in_b1, in_b2, out_w1, out_b1, out_w2, out_b2,
                                  out_pts);
  dim3 gs(HWp / 256, 2 * Bb);
  scatter_k<<<gs, 256, 0, stream>>>(grids, li_coors, ra_coors, out_pts,
                                    (float*)d_out);
}

// Round 10
// 92.872 us; speedup vs baseline: 3.4152x; 1.3690x over previous
//
#include <hip/hip_runtime.h>

constexpr int Hh = 320, Ww = 320, Cc = 32, Bb = 4, Nn = 20000;
constexpr int HWp = Hh * Ww;

__device__ __forceinline__ float4 shfl_xor4(float4 v, int m) {
  return make_float4(__shfl_xor(v.x, m), __shfl_xor(v.y, m),
                     __shfl_xor(v.z, m), __shfl_xor(v.w, m));
}

// prep: blocks [0,800) fill grids with -1 (int4, full BW); blocks [800,803)
// compute posv[dir][l][c] = pos[l] @ wv_dir.T
__global__ __launch_bounds__(256) void prep_k(
    int* __restrict__ grids, const float* __restrict__ pos,
    const float* __restrict__ in_w1, const float* __restrict__ in_w2,
    float* __restrict__ posv) {
  int bx = blockIdx.x;
  if (bx < 800) {
    int i = bx * 256 + threadIdx.x;  // 800*256 int4 = 2*4*HWp ints exactly
    ((int4*)grids)[i] = make_int4(-1, -1, -1, -1);
    return;
  }
  int t = (bx - 800) * 256 + threadIdx.x;
  if (t >= 2 * 9 * Cc) return;
  int dir = t / (9 * Cc);
  int rem = t - dir * 9 * Cc;
  int l = rem / Cc, ch = rem - l * Cc;
  const float* w = (dir == 0 ? in_w1 : in_w2) + (2 * Cc + ch) * Cc;
  const float* pl = pos + l * Cc;
  float acc = 0.f;
  for (int j = 0; j < Cc; j++) acc += pl[j] * w[j];
  posv[t] = acc;
}

// Fused: blocks [0, PROJ_TOTAL) = Q/K/V projection (register-tiled, 4 pts/thread);
// blocks [PROJ_TOTAL, +BUILD_BLOCKS) = build_grid scatter (grid pre-filled).
constexpr int PROJ_BLOCKS_PER_SB = 157;              // ceil(20000/128)
constexpr int PROJ_TOTAL = PROJ_BLOCKS_PER_SB * 8;   // 1256
constexpr int BUILD_BLOCKS = 625;                    // 160000/256 exact

__global__ __launch_bounds__(256) void project_build_k(
    const float* __restrict__ li_feats, const float* __restrict__ ra_feats,
    const int* __restrict__ li_coors, const int* __restrict__ ra_coors,
    const float* __restrict__ in_w1, const float* __restrict__ in_b1,
    const float* __restrict__ in_w2, const float* __restrict__ in_b2,
    float* __restrict__ Qh, float* __restrict__ Kp, float* __restrict__ Vp,
    int* __restrict__ grids) {
  int bx = blockIdx.x;
  if (bx >= PROJ_TOTAL) {
    int idx = (bx - PROJ_TOTAL) * 256 + threadIdx.x;  // [0, 160000) exact
    int src = idx / (Bb * Nn);
    int r = idx - src * (Bb * Nn);
    int b = r / Nn, n = r - b * Nn;
    const int* c = (src == 0 ? li_coors : ra_coors) + ((size_t)b * Nn + n) * 2;
    grids[((size_t)src * Bb + b) * HWp + c[0] * Ww + c[1]] = n;
    return;
  }
  int sb = bx / PROJ_BLOCKS_PER_SB;
  int blk = bx - sb * PROJ_BLOCKS_PER_SB;
  int src = sb >> 2, b = sb & 3;
  // weights transposed, rows padded to 36 floats (9 float4) for bank spread
  __shared__ __align__(16) float wqT[32 * 36];
  __shared__ __align__(16) float wkT[32 * 36];
  __shared__ __align__(16) float wvT[32 * 36];
  __shared__ float bq[Cc];
  const float* wA = src == 0 ? in_w1 : in_w2;  // q weights: own direction
  const float* bA = src == 0 ? in_b1 : in_b2;
  const float* wB = src == 0 ? in_w2 : in_w1;  // k/v weights: other direction
  int t = threadIdx.x;
  for (int i = t; i < Cc * Cc; i += 256) {
    int c = i >> 5, j = i & 31;
    wqT[j * 36 + c] = wA[i];
    wkT[j * 36 + c] = wB[Cc * Cc + i];
    wvT[j * 36 + c] = wB[2 * Cc * Cc + i];
  }
  if (t < Cc) bq[t] = bA[t];
  __syncthreads();
  int quad = t >> 3, c4 = t & 7;
  int n0 = blk * 128 + quad * 4;
  if (n0 + 4 > Nn) n0 = Nn - 4;  // tail clamp: redundant idempotent work
  const float* f = (src == 0 ? li_feats : ra_feats) + ((size_t)b * Nn + n0) * Cc;
  const float4* wq4 = (const float4*)wqT;
  const float4* wk4 = (const float4*)wkT;
  const float4* wv4 = (const float4*)wvT;
  float4 bq4 = *(const float4*)(bq + c4 * 4);
  float4 aq[4], ak[4], av[4];
#pragma unroll
  for (int i = 0; i < 4; i++) {
    aq[i] = bq4;
    ak[i] = make_float4(0.f, 0.f, 0.f, 0.f);
    av[i] = make_float4(0.f, 0.f, 0.f, 0.f);
  }
#pragma unroll
  for (int j4 = 0; j4 < 8; j4++) {
    float fjs[4][4];
#pragma unroll
    for (int i = 0; i < 4; i++) {
      float4 v = ((const float4*)(f + i * Cc))[j4];
      fjs[i][0] = v.x; fjs[i][1] = v.y; fjs[i][2] = v.z; fjs[i][3] = v.w;
    }
#pragma unroll
    for (int u = 0; u < 4; u++) {
      int j = j4 * 4 + u;
      float4 q4 = wq4[j * 9 + c4];
      float4 k4 = wk4[j * 9 + c4];
      float4 v4 = wv4[j * 9 + c4];
#pragma unroll
      for (int i = 0; i < 4; i++) {
        float fj = fjs[i][u];
        aq[i].x += fj * q4.x; aq[i].y += fj * q4.y;
        aq[i].z += fj * q4.z; aq[i].w += fj * q4.w;
        ak[i].x += fj * k4.x; ak[i].y += fj * k4.y;
        ak[i].z += fj * k4.z; ak[i].w += fj * k4.w;
        av[i].x += fj * v4.x; av[i].y += fj * v4.y;
        av[i].z += fj * v4.z; av[i].w += fj * v4.w;
      }
    }
  }
  int dirkv = 1 - src;
  size_t qbase = (((size_t)src * Bb + b) * Nn + n0) * Cc + c4 * 4;
  size_t kvbase = (((size_t)dirkv * Bb + b) * Nn + n0) * Cc + c4 * 4;
#pragma unroll
  for (int i = 0; i < 4; i++) {
    *(float4*)(Qh + qbase + i * Cc) = aq[i];
    *(float4*)(Kp + kvbase + i * Cc) = ak[i];
    *(float4*)(Vp + kvbase + i * Cc) = av[i];
  }
}

// 8-lane-per-point attention + in-kernel output projection.
// Latency-optimized: compute all 9 sel (1-deep), then issue ALL 18 K/V gathers
// upfront into registers (independent, one drain), then run dots/softmax/PV
// entirely from registers. Lane owns channels [4*c4, 4*c4+4).
__global__ __launch_bounds__(256) void attn8_k(
    const int* __restrict__ li_coors, const int* __restrict__ ra_coors,
    const int* __restrict__ grids, const float* __restrict__ Qh,
    const float* __restrict__ Kp, const float* __restrict__ Vp,
    const float* __restrict__ posv, const float* __restrict__ in_b1,
    const float* __restrict__ in_b2, const float* __restrict__ out_w1,
    const float* __restrict__ out_b1, const float* __restrict__ out_w2,
    const float* __restrict__ out_b2, float* __restrict__ out_pts) {
  int db = blockIdx.y;
  int dir = db >> 2, b = db & 3;
  __shared__ __align__(16) float ow[Cc * Cc];
  __shared__ __align__(16) float pv[9 * Cc];
  __shared__ float sbk[Cc], sbv[Cc], sob[Cc];
  const float* owp = dir == 0 ? out_w1 : out_w2;
  const float* obp = dir == 0 ? out_b1 : out_b2;
  const float* ibp = dir == 0 ? in_b1 : in_b2;
  int t = threadIdx.x;
  for (int i = t; i < Cc * Cc; i += 256) ow[i] = owp[i];
  for (int i = t; i < 9 * Cc; i += 256) pv[i] = posv[dir * 9 * Cc + i];
  if (t < Cc) {
    sbk[t] = ibp[Cc + t];
    sbv[t] = ibp[2 * Cc + t];
    sob[t] = obp[t];
  }
  __syncthreads();
  int pt = t >> 3, c4 = t & 7;
  int n = blockIdx.x * 32 + pt;  // 625*32 == 20000 exact, no tail
  const int2* qcp =
      (const int2*)((dir == 0 ? li_coors : ra_coors) + (size_t)b * Nn * 2);
  int2 yx = qcp[n];
  int y = yx.x, x = yx.y;
  const int* g = grids + ((size_t)(1 - dir) * Bb + b) * HWp;
  const int DY[9] = {0, -1, 1, 0, -1, 1, 0, -1, 1};
  const int DX[9] = {0, 0, 0, 1, 1, 1, -1, -1, -1};
  // ---- phase 1: all 9 sel loads (independent, 1-deep; grid pre-filled)
  int sel[9];
#pragma unroll
  for (int l = 0; l < 9; l++) {
    int cy = y + DY[l], cx = x + DX[l];
    sel[l] = ((unsigned)cy < (unsigned)Hh && (unsigned)cx < (unsigned)Ww)
                 ? g[cy * Ww + cx]
                 : -1;
  }
  // ---- phase 2: issue all K/V gathers into registers (zero when invalid)
  const float* Kpb = Kp + ((size_t)dir * Bb + b) * Nn * Cc;
  const float* Vpb = Vp + ((size_t)dir * Bb + b) * Nn * Cc;
  float4 k4s[9], v4s[9];
#pragma unroll
  for (int l = 0; l < 9; l++) {
    float4 kk = make_float4(0.f, 0.f, 0.f, 0.f);
    float4 vv = make_float4(0.f, 0.f, 0.f, 0.f);
    int se = sel[l];
    if (se >= 0) {
      kk = *(const float4*)(Kpb + (size_t)se * Cc + c4 * 4);
      vv = *(const float4*)(Vpb + (size_t)se * Cc + c4 * 4);
    }
    k4s[l] = kk;
    v4s[l] = vv;
  }
  float4 qh4 =
      *(const float4*)(Qh + (((size_t)dir * Bb + b) * Nn + n) * Cc + c4 * 4);
  // invalid-slot score: qh . bk over the lane's head (reduce within 4 lanes)
  float4 bk4 = *(const float4*)(sbk + c4 * 4);
  float pb = qh4.x * bk4.x + qh4.y * bk4.y + qh4.z * bk4.z + qh4.w * bk4.w;
  pb += __shfl_xor(pb, 1);
  pb += __shfl_xor(pb, 2);
  // ---- phase 3: scores from registers (k4s=0 for invalid -> d=0 -> s=pb/4)
  float s[9];
#pragma unroll
  for (int l = 0; l < 9; l++) {
    float4 k4 = k4s[l];
    float d = qh4.x * k4.x + qh4.y * k4.y + qh4.z * k4.z + qh4.w * k4.w;
    d += __shfl_xor(d, 1);
    d += __shfl_xor(d, 2);  // lane's head dot
    s[l] = 0.25f * (pb + d);
  }
  // softmax over 9 slots for the lane's head
  float m = s[0];
#pragma unroll
  for (int l = 1; l < 9; l++) m = fmaxf(m, s[l]);
  float sum = 0.f;
#pragma unroll
  for (int l = 0; l < 9; l++) {
    s[l] = __expf(s[l] - m);
    sum += s[l];
  }
  // ---- phase 4: PV from registers (posv only for valid slots)
  float4 o4 = make_float4(0.f, 0.f, 0.f, 0.f);
#pragma unroll
  for (int l = 0; l < 9; l++) {
    float wp = (sel[l] >= 0) ? s[l] : 0.f;
    float4 v4 = v4s[l];
    float4 p4 = *(const float4*)(pv + l * Cc + c4 * 4);
    o4.x += wp * (v4.x + p4.x);
    o4.y += wp * (v4.y + p4.y);
    o4.z += wp * (v4.z + p4.z);
    o4.w += wp * (v4.w + p4.w);
  }
  float r = 1.f / sum;
  float4 bv4 = *(const float4*)(sbv + c4 * 4);
  o4 = make_float4(o4.x * r + bv4.x, o4.y * r + bv4.y, o4.z * r + bv4.z,
                   o4.w * r + bv4.w);
  // output projection: lane computes out channels [4*c4, 4*c4+4)
  const float4* ow4 = (const float4*)ow;
  float4 sob4 = *(const float4*)(sob + c4 * 4);
  float acc0 = sob4.x, acc1 = sob4.y, acc2 = sob4.z, acc3 = sob4.w;
#pragma unroll
  for (int mm = 0; mm < 8; mm++) {
    float4 oj = shfl_xor4(o4, mm);  // o slice of group jb = c4 ^ mm
    int jb = c4 ^ mm;
    float4 w0 = ow4[(c4 * 4 + 0) * 8 + jb];
    float4 w1 = ow4[(c4 * 4 + 1) * 8 + jb];
    float4 w2 = ow4[(c4 * 4 + 2) * 8 + jb];
    float4 w3 = ow4[(c4 * 4 + 3) * 8 + jb];
    acc0 += oj.x * w0.x + oj.y * w0.y + oj.z * w0.z + oj.w * w0.w;
    acc1 += oj.x * w1.x + oj.y * w1.y + oj.z * w1.z + oj.w * w1.w;
    acc2 += oj.x * w2.x + oj.y * w2.y + oj.z * w2.z + oj.w * w2.w;
    acc3 += oj.x * w3.x + oj.y * w3.y + oj.z * w3.z + oj.w * w3.w;
  }
  *(float4*)(out_pts + (((size_t)dir * Bb + b) * Nn + n) * Cc + c4 * 4) =
      make_float4(acc0, acc1, acc2, acc3);
}

// Inverted scatter: grid pre-filled, no verify. One thread per canvas pixel;
// channel stores are wave-coalesced full lines.
__global__ __launch_bounds__(256) void scatter_k(
    const int* __restrict__ grids, const float* __restrict__ out_pts,
    float* __restrict__ out) {
  int db = blockIdx.y;
  int dir = db >> 2, b = db & 3;
  int p = blockIdx.x * 256 + threadIdx.x;
  const int* gq = grids + ((size_t)dir * Bb + b) * HWp;
  int se = gq[p];
  float* ob = out + (((size_t)dir * Bb + b) * Cc) * HWp + p;
  if (se < 0) {
#pragma unroll
    for (int c = 0; c < Cc; c++) ob[(size_t)c * HWp] = 0.f;
  } else {
    const float4* sp =
        (const float4*)(out_pts + (((size_t)dir * Bb + b) * Nn + se) * Cc);
#pragma unroll
    for (int c4 = 0; c4 < 8; c4++) {
      float4 v = sp[c4];
      ob[(size_t)(c4 * 4 + 0) * HWp] = v.x;
      ob[(size_t)(c4 * 4 + 1) * HWp] = v.y;
      ob[(size_t)(c4 * 4 + 2) * HWp] = v.z;
      ob[(size_t)(c4 * 4 + 3) * HWp] = v.w;
    }
  }
}

extern "C" void kernel_launch(void* const* d_in, const int* in_sizes, int n_in,
                              void* d_out, int out_size, void* d_ws, size_t ws_size,
                              hipStream_t stream) {
  const float* li_feats = (const float*)d_in[0];
  const int* li_coors = (const int*)d_in[1];
  const float* ra_feats = (const float*)d_in[2];
  const int* ra_coors = (const int*)d_in[3];
  const float* pos = (const float*)d_in[4];
  const float* in_w1 = (const float*)d_in[5];
  const float* in_b1 = (const float*)d_in[6];
  const float* out_w1 = (const float*)d_in[7];
  const float* out_b1 = (const float*)d_in[8];
  const float* in_w2 = (const float*)d_in[9];
  const float* in_b2 = (const float*)d_in[10];
  const float* out_w2 = (const float*)d_in[11];
  const float* out_b2 = (const float*)d_in[12];

  char* ws = (char*)d_ws;
  size_t off = 0;
  int* grids = (int*)(ws + off);
  off += (size_t)2 * Bb * HWp * 4;  // 3,276,800 B
  float* Qh = (float*)(ws + off);
  off += (size_t)2 * Bb * Nn * Cc * 4;  // 20,480,000 B
  float* Kp = (float*)(ws + off);
  off += (size_t)2 * Bb * Nn * Cc * 4;
  float* Vp = (float*)(ws + off);
  off += (size_t)2 * Bb * Nn * Cc * 4;
  float* out_pts = (float*)(ws + off);
  off += (size_t)2 * Bb * Nn * Cc * 4;
  float* posv = (float*)(ws + off);
  off += 2 * 9 * Cc * 4;  // total ~85.2 MB

  prep_k<<<803, 256, 0, stream>>>(grids, pos, in_w1, in_w2, posv);
  project_build_k<<<PROJ_TOTAL + BUILD_BLOCKS, 256, 0, stream>>>(
      li_feats, ra_feats, li_coors, ra_coors, in_w1, in_b1, in_w2, in_b2, Qh, Kp,
      Vp, grids);
  dim3 ga(Nn / 32, 2 * Bb);
  attn8_k<<<ga, 256, 0, stream>>>(li_coors, ra_coors, grids, Qh, Kp, Vp, posv,
                                  in_b1, in_b2, out_w1, out_b1, out_w2, out_b2,
                                  out_pts);
  dim3 gs(HWp / 256, 2 * Bb);
  scatter_k<<<gs, 256, 0, stream>>>(grids, out_pts, (float*)d_out);
}